// Round 13
// baseline (181.224 us; speedup 1.0000x reference)
//
#include <hip/hip_runtime.h>
#include <hip/hip_fp16.h>
#include <math.h>

#define H 256
#define W 256
#define HW (H * W)
#define B 2
#define V 3
#define BV (B * V)
#define C 32
#define RADIUS 1.5f
#define TAU 1.0f
#define EPS 1e-8f

#define NPIX (BV * HW)    // 393216 destination pixels (= source points)
#define NBLK (NPIX / 256) // 1536 (divisible by 8 -> bijective XCD swizzle)

// Cell grid: one bin per ROUNDED projected position, 1-pixel halo.
#define GW 258
#define GH 258
#define NCELL (BV * GH * GW)           // 399384 cells (+1 sentinel)
#define NSUMS ((NCELL + 255) / 256)    // 1561 alloc blocks
#define ECAP 368                       // staged entries per tile halo (mean ~295)

// XCD-aware chunked swizzle (NBLK divisible by 8 -> bijective).
__device__ __forceinline__ int swizzle_block(int bid) {
    return (bid & 7) * (NBLK / 8) + (bid >> 3);
}

// ---------------------------------------------------------------------------
// Fold the projection chain into one matrix (per bv):
//   M = K[b] * dst_RT[b] * src_RTinv[b,v] * inv(K[b])
// Executed by thread 0 of each project block (~400 serial FLOPs, hidden by
// co-resident blocks). NO separate setup dispatch, NO fences.
// ---------------------------------------------------------------------------
__device__ void compute_M(int bv, const float* __restrict__ Kmat,
                          const float* __restrict__ srcRTinv,
                          const float* __restrict__ dstRT,
                          float* __restrict__ Mout) {
    int b = bv / V;
    float a[4][8];
    for (int i = 0; i < 4; i++)
        for (int j = 0; j < 4; j++) {
            a[i][j] = Kmat[b * 16 + i * 4 + j];
            a[i][4 + j] = (i == j) ? 1.0f : 0.0f;
        }
    for (int col = 0; col < 4; col++) {
        int piv = col;
        float best = fabsf(a[col][col]);
        for (int r = col + 1; r < 4; r++) {
            float v = fabsf(a[r][col]);
            if (v > best) { best = v; piv = r; }
        }
        if (piv != col) {
            for (int j = 0; j < 8; j++) {
                float t = a[col][j]; a[col][j] = a[piv][j]; a[piv][j] = t;
            }
        }
        float s = 1.0f / a[col][col];
        for (int j = 0; j < 8; j++) a[col][j] *= s;
        for (int r = 0; r < 4; r++) {
            if (r == col) continue;
            float m = a[r][col];
            for (int j = 0; j < 8; j++) a[r][j] -= m * a[col][j];
        }
    }
    float Kinv[16];
    for (int i = 0; i < 4; i++)
        for (int j = 0; j < 4; j++) Kinv[i * 4 + j] = a[i][4 + j];

    float T1[16];
    const float* S = srcRTinv + bv * 16;
    for (int i = 0; i < 4; i++)
        for (int j = 0; j < 4; j++) {
            float acc = 0.0f;
            for (int k = 0; k < 4; k++) acc += S[i * 4 + k] * Kinv[k * 4 + j];
            T1[i * 4 + j] = acc;
        }
    float T2[16];
    const float* D = dstRT + b * 16;
    for (int i = 0; i < 4; i++)
        for (int j = 0; j < 4; j++) {
            float acc = 0.0f;
            for (int k = 0; k < 4; k++) acc += D[i * 4 + k] * T1[k * 4 + j];
            T2[i * 4 + j] = acc;
        }
    const float* Kb = Kmat + b * 16;
    for (int i = 0; i < 4; i++)
        for (int j = 0; j < 4; j++) {
            float acc = 0.0f;
            for (int k = 0; k < 4; k++) acc += Kb[i * 4 + k] * T2[k * 4 + j];
            Mout[i * 4 + j] = acc;
        }
}

// ---------------------------------------------------------------------------
// Pass 1: setup-M (thread 0 -> LDS) + project + count. Writes ONE coalesced
// 16B staging record per point {px, py, z, cell_as_bits} (cell = -1 if the
// point can't touch any in-image tap) and bumps the cell count. Later passes
// COPY from staging (never reproject) => bit-identical by construction.
// ---------------------------------------------------------------------------
__global__ __launch_bounds__(256) void project_count_kernel(
    const float* __restrict__ depths, const float* __restrict__ Kmat,
    const float* __restrict__ srcRTinv, const float* __restrict__ dstRT,
    float4* __restrict__ staging, int2* __restrict__ meta) {
    __shared__ float Msh[16];
    int gid = swizzle_block(blockIdx.x) * 256 + threadIdx.x;
    int bv = gid >> 16;
    int n = gid & (HW - 1);
    if (threadIdx.x == 0) compute_M(bv, Kmat, srcRTinv, dstRT, Msh);
    __syncthreads();

    float xn = (float)(n & (W - 1)) * (2.0f / (W - 1)) - 1.0f;
    float yn = (float)(n >> 8)      * (2.0f / (H - 1)) - 1.0f;
    float d = depths[gid];
    float X = xn * d, Y = yn * d;
    float p0 = Msh[0] * X + Msh[1] * Y + Msh[2]  * d + Msh[3];
    float p1 = Msh[4] * X + Msh[5] * Y + Msh[6]  * d + Msh[7];
    float z  = Msh[8] * X + Msh[9] * Y + Msh[10] * d + Msh[11];

    int cell = -1;
    float px = 0.0f, py = 0.0f;
    if (z > 0.0f) {  // reference masks z<=0 taps entirely
        float inv = 1.0f / (z + EPS);
        px = (p0 * inv + 1.0f) * 0.5f * (float)(W - 1);
        py = (p1 * inv + 1.0f) * 0.5f * (float)(H - 1);
        float rx = rintf(px), ry = rintf(py);
        // rounding outside the 1-px halo -> no in-image tap with weight > 0
        if (rx >= -1.0f && rx <= (float)W && ry >= -1.0f && ry <= (float)H) {
            cell = bv * (GH * GW) + ((int)ry + 1) * GW + ((int)rx + 1);
            atomicAdd(&meta[cell].y, 1);
        }
    }
    staging[gid] = make_float4(px, py, z, __int_as_float(cell));
}

// ---------------------------------------------------------------------------
// Pass 2a: block-local exclusive scan of counts. meta[i].x = local exclusive
// offset within this 256-cell block; bsum[blk] = block total. DETERMINISTIC
// (no global atomic) so the final CSR is in cell order => start(c+1)==end(c)
// for ALL cells. Covers i == NCELL (sentinel, count 0 from memset).
// SEPARATE dispatch from 2b: r11 measured per-block device fences at 128us;
// a 1-block dispatch is ~2-3us. Do NOT fuse.
// ---------------------------------------------------------------------------
__global__ __launch_bounds__(256) void alloc1_kernel(int2* __restrict__ meta,
                                                     int* __restrict__ bsum) {
    int i = blockIdx.x * 256 + threadIdx.x;
    int c = (i < NCELL) ? meta[i].y : 0;
    int lane = threadIdx.x & 63;
    int wid = threadIdx.x >> 6;
    int x = c;  // inclusive scan within wave
#pragma unroll
    for (int dlt = 1; dlt < 64; dlt <<= 1) {
        int y = __shfl_up(x, dlt);
        if (lane >= dlt) x += y;
    }
    __shared__ int wsum[4];
    __shared__ int wbase[4];
    if (lane == 63) wsum[wid] = x;
    __syncthreads();
    if (threadIdx.x == 0) {
        int s0 = wsum[0], s1 = wsum[1], s2 = wsum[2], s3 = wsum[3];
        wbase[0] = 0; wbase[1] = s0; wbase[2] = s0 + s1; wbase[3] = s0 + s1 + s2;
        bsum[blockIdx.x] = s0 + s1 + s2 + s3;
    }
    __syncthreads();
    if (i <= NCELL) meta[i].x = wbase[wid] + (x - c);
}

// ---------------------------------------------------------------------------
// Pass 2b: exclusive scan of the 1561 block sums, single block, serial
// chunks of 256 with a running carry.
// ---------------------------------------------------------------------------
__global__ __launch_bounds__(256) void alloc2_kernel(int* __restrict__ bsum) {
    __shared__ int wsum[4];
    __shared__ int wbase[4];
    __shared__ int carry_s;
    int tid = threadIdx.x;
    int lane = tid & 63;
    int wid = tid >> 6;
    if (tid == 0) carry_s = 0;
    __syncthreads();
    const int nchunk = (NSUMS + 255) / 256;
    for (int ch = 0; ch < nchunk; ch++) {
        int i = ch * 256 + tid;
        int c = (i < NSUMS) ? bsum[i] : 0;
        int x = c;
#pragma unroll
        for (int dlt = 1; dlt < 64; dlt <<= 1) {
            int y = __shfl_up(x, dlt);
            if (lane >= dlt) x += y;
        }
        if (lane == 63) wsum[wid] = x;
        __syncthreads();
        if (tid == 0) {
            int cr = carry_s;
            int s0 = wsum[0], s1 = wsum[1], s2 = wsum[2], s3 = wsum[3];
            wbase[0] = cr; wbase[1] = cr + s0; wbase[2] = cr + s0 + s1;
            wbase[3] = cr + s0 + s1 + s2;
            carry_s = cr + s0 + s1 + s2 + s3;
        }
        __syncthreads();
        if (i < NSUMS) bsum[i] = wbase[wid] + (x - c);
        __syncthreads();
    }
}

// ---------------------------------------------------------------------------
// Pass 3: fill (absorbs the transpose). Per block: LDS-stage a 256-point
// feats chunk (coalesced), then each thread copies its point's staging
// record to entries16[pos] = {px,py,z, wd=exp(-tau*z)} and writes the 64B
// fp16 feature record at entriesF[pos]. pos = scanned block base + local
// atomic bump => CSR in cell order. The scattered 64B record writes are
// full-sector (64B-aligned) => no write amplification (r9 measured).
// ---------------------------------------------------------------------------
__global__ __launch_bounds__(256) void fill_kernel(
    const float* __restrict__ feats, const float4* __restrict__ staging,
    const int* __restrict__ bsum, int2* __restrict__ meta,
    float4* __restrict__ entries16, uint4* __restrict__ entriesF) {
    __shared__ float sm[C][257];
    int blk = blockIdx.x;
    int bv = blk >> 8;
    int n0 = (blk & 255) << 8;
    int tid = threadIdx.x;
    const float* src = feats + (size_t)bv * C * HW + n0;
#pragma unroll
    for (int c = 0; c < C; c++) sm[c][tid] = src[(size_t)c * HW + tid];
    __syncthreads();

    int gid = (bv << 16) | (n0 + tid);
    float4 s = staging[gid];
    int cell = __float_as_int(s.w);
    if (cell < 0) return;
    int pos = bsum[cell >> 8] + atomicAdd(&meta[cell].x, 1);

    float wd = expf(-TAU * s.z);  // once per point (not per tap)
    entries16[pos] = make_float4(s.x, s.y, s.z, wd);

    uint4* dst = entriesF + (size_t)pos * 4;
#pragma unroll
    for (int g = 0; g < 4; g++) {
        __half2 h0 = __floats2half2_rn(sm[g * 8 + 0][tid], sm[g * 8 + 1][tid]);
        __half2 h1 = __floats2half2_rn(sm[g * 8 + 2][tid], sm[g * 8 + 3][tid]);
        __half2 h2 = __floats2half2_rn(sm[g * 8 + 4][tid], sm[g * 8 + 5][tid]);
        __half2 h3 = __floats2half2_rn(sm[g * 8 + 6][tid], sm[g * 8 + 7][tid]);
        uint4 pk;
        pk.x = *(unsigned int*)&h0;
        pk.y = *(unsigned int*)&h1;
        pk.z = *(unsigned int*)&h2;
        pk.w = *(unsigned int*)&h3;
        dst[g] = pk;  // 64B record, 64B-aligned
    }
}

// ---------------------------------------------------------------------------
// Pass 4: TILED gather (r12 structure). UNIFIED LDS: the stride-5 feature
// array's pad slot (idx*5+4) now holds the 16B test record, eliminating the
// separate lds_e (6KB). LDS 38.5 -> 31.0 KB => 5 blocks/CU (+25% waves on
// this latency-bound kernel). Same coalesced staging, same branch-free body
// (w == 0 exactly on rejects), same bank pattern, exact same math.
// ---------------------------------------------------------------------------
__global__ __launch_bounds__(256) void gather_kernel(
    const float4* __restrict__ entries16, const uint4* __restrict__ entriesF,
    const int2* __restrict__ meta, const int* __restrict__ bsum,
    float* __restrict__ out) {
    __shared__ int cs_s[18][19];
    __shared__ int row_rs[18];   // global CSR start of row
    __shared__ int row_off[18];  // compact LDS offset of row
    __shared__ int row_sl[18];   // staged length of row
    __shared__ uint4 lds_f[ECAP * 5];  // [idx*5+g] g=0..3 features, g=4 test

    int sblk = swizzle_block(blockIdx.x);
    int bv = sblk >> 8;
    int t = sblk & 255;
    int ty0 = (t >> 4) << 4;   // tile origin in dest coords
    int tx0 = (t & 15) << 4;
    int tid = threadIdx.x;
    int cellbase = bv * (GH * GW);

    // Phase A: global CSR start offset for each of the 18x19 halo cells.
    // Column 18 = start of the next linear cell == end of column 17
    // (contiguity); the +1 sentinel cell (== total) covers the last span.
    for (int i = tid; i < 18 * 19; i += 256) {
        int hr = i / 19, lc = i - hr * 19;
        int cg = cellbase + (ty0 + hr) * GW + (tx0 + lc);
        int2 m = meta[cg];
        cs_s[hr][lc] = bsum[cg >> 8] + m.x - m.y;  // after fill: x=end(local)
    }
    __syncthreads();
    // Phase A2: wave-parallel packing-offset scan over the 18 rows.
    if (tid < 32) {
        int l = tid;
        int start = 0, len = 0;
        if (l < 18) { start = cs_s[l][0]; len = cs_s[l][18] - start; }
        int x = len;
#pragma unroll
        for (int dlt = 1; dlt < 32; dlt <<= 1) {
            int y = __shfl_up(x, dlt);
            if (l >= dlt) x += y;
        }
        if (l < 18) {
            int off = x - len;
            row_rs[l] = start;
            row_off[l] = off;
            int sl = ECAP - off;
            sl = min(sl, len);
            if (sl < 0) sl = 0;
            row_sl[l] = sl;
        }
    }
    __syncthreads();
    // Phase B: stage test + feature records; wave w handles rows w, w+4, ...
    {
        int wid = tid >> 6, lane = tid & 63;
        for (int hr = wid; hr < 18; hr += 4) {
            int rs = row_rs[hr], off = row_off[hr], sl = row_sl[hr];
            for (int j = lane; j < sl; j += 64)  // test record -> pad slot 4
                lds_f[(off + j) * 5 + 4] = *(const uint4*)&entries16[rs + j];
            int j0 = lane >> 2, g = lane & 3;
            for (int j = j0; j < sl; j += 16)  // 64 lanes = 1KB contiguous
                lds_f[(off + j) * 5 + g] = entriesF[(size_t)(rs + j) * 4 + g];
        }
    }
    __syncthreads();

    int lx = tid & 15, ly = tid >> 4;
    float qx = (float)(tx0 + lx);
    float qy = (float)(ty0 + ly);

    float wsum = 0.0f, zwsum = 0.0f;
    float facc[C];
#pragma unroll
    for (int c = 0; c < C; c++) facc[c] = 0.0f;

    // Branch-free LDS body: w == 0 exactly for rejected entries.
    auto body = [&](int li) {
        uint4 tv = lds_f[li * 5 + 4];
        float4 v = *(const float4*)&tv;
        uint4 fv0 = lds_f[li * 5 + 0];
        uint4 fv1 = lds_f[li * 5 + 1];
        uint4 fv2 = lds_f[li * 5 + 2];
        uint4 fv3 = lds_f[li * 5 + 3];
        float ddx = qx - v.x, ddy = qy - v.y;
        float dist = sqrtf(ddx * ddx + ddy * ddy + EPS);
        float wr = fmaxf(0.0f, 1.0f - dist * (1.0f / RADIUS));
        float w = wr * v.w;  // v.w = exp(-tau*z); w = 0 on reject
        wsum += w;
        zwsum += v.z * w;
        const uint4* fvs[4] = {&fv0, &fv1, &fv2, &fv3};
#pragma unroll
        for (int g = 0; g < 4; g++) {
            const __half2* h2 = (const __half2*)fvs[g];
#pragma unroll
            for (int k = 0; k < 4; k++) {
                float2 f2 = __half22float2(h2[k]);
                facc[g * 8 + 2 * k]     = fmaf(w, f2.x, facc[g * 8 + 2 * k]);
                facc[g * 8 + 2 * k + 1] = fmaf(w, f2.y, facc[g * 8 + 2 * k + 1]);
            }
        }
    };
    auto accum_glb = [&](int pos) {  // exact overflow fallback (rare)
        float4 v = entries16[pos];
        float ddx = qx - v.x, ddy = qy - v.y;
        float d2 = ddx * ddx + ddy * ddy + EPS;
        if (d2 < RADIUS * RADIUS) {
            float dist = sqrtf(d2);
            float wr = 1.0f - dist * (1.0f / RADIUS);
            float w = wr * v.w;
            wsum += w;
            zwsum += v.z * w;
            const uint4* fp = entriesF + (size_t)pos * 4;
#pragma unroll
            for (int g = 0; g < 4; g++) {
                uint4 fv = fp[g];
                const __half2* h2 = (const __half2*)&fv;
#pragma unroll
                for (int k = 0; k < 4; k++) {
                    float2 f2 = __half22float2(h2[k]);
                    facc[g * 8 + 2 * k]     = fmaf(w, f2.x, facc[g * 8 + 2 * k]);
                    facc[g * 8 + 2 * k + 1] = fmaf(w, f2.y, facc[g * 8 + 2 * k + 1]);
                }
            }
        }
    };

#pragma unroll
    for (int dy = 0; dy < 3; dy++) {
        int hr = ly + dy;
        int s = cs_s[hr][lx];
        int e = cs_s[hr][lx + 3];
        int rs = row_rs[hr];
        int off = row_off[hr];
        int sEnd = rs + row_sl[hr];
        int e1 = min(e, sEnd);
        int li0 = off + (s - rs);
        int cnt = e1 - s;
        int j = 0;
        for (; j + 2 <= cnt; j += 2) {  // x2 unrolled, independent bodies
            body(li0 + j);
            body(li0 + j + 1);
        }
        if (j < cnt) body(li0 + j);
        for (int pos = max(s, sEnd); pos < e; ++pos) accum_glb(pos);
    }

    int q = ((ty0 + ly) << 8) | (tx0 + lx);
    int gid = (bv << 16) | q;
    float invw = 1.0f / (wsum + EPS);
    float* ob = out + (size_t)bv * C * HW + q;
#pragma unroll
    for (int c = 0; c < C; c++) ob[(size_t)c * HW] = facc[c] * invw;
    out[(size_t)BV * C * HW + gid] = zwsum * invw;
}

extern "C" void kernel_launch(void* const* d_in, const int* in_sizes, int n_in,
                              void* d_out, int out_size, void* d_ws, size_t ws_size,
                              hipStream_t stream) {
    const float* depths   = (const float*)d_in[0];  // (B,V,1,H,W)
    const float* feats    = (const float*)d_in[1];  // (B,V,C,H,W)
    const float* Kmat     = (const float*)d_in[2];  // (B,4,4)
    const float* srcRTinv = (const float*)d_in[4];  // (B,V,4,4)
    const float* dstRT    = (const float*)d_in[5];  // (B,1,4,4)
    float* out = (float*)d_out;

    // ws layout:
    //   entriesF  : NPIX * 64B fp16 records (CSR pos-indexed)  25.17 MB
    //   entries16 : NPIX * float4 {px,py,z,wd}                  6.29 MB
    //   staging   : NPIX * float4 {px,py,z,cell}                6.29 MB
    //   meta      : (NCELL+1) int2 {ofs,cnt}                    3.20 MB
    //   bsum      : NSUMS int                                   6.2 KB
    // total ~41 MB (<= 63 MB proven available)
    char* ws = (char*)d_ws;
    size_t off_entriesF = 0;
    size_t off_entries16 = off_entriesF + (size_t)NPIX * 64;
    size_t off_staging = off_entries16 + (size_t)NPIX * 16;
    size_t off_meta = off_staging + (size_t)NPIX * 16;
    size_t off_bsum = off_meta + (size_t)(NCELL + 1) * 8;
    size_t needed = off_bsum + (size_t)NSUMS * 4 + 16;

    if (ws_size < needed) {
        hipMemsetAsync(d_out, 0, (size_t)out_size * 4, stream);
        return;
    }

    uint4* entriesF   = (uint4*)(ws + off_entriesF);
    float4* entries16 = (float4*)(ws + off_entries16);
    float4* staging   = (float4*)(ws + off_staging);
    int2* meta        = (int2*)(ws + off_meta);
    int* bsum         = (int*)(ws + off_bsum);

    // zero meta {ofs,cnt} incl. sentinel (bsum fully written by alloc1)
    hipMemsetAsync(meta, 0, (size_t)(NCELL + 1) * 8, stream);
    project_count_kernel<<<NBLK, 256, 0, stream>>>(depths, Kmat, srcRTinv,
                                                   dstRT, staging, meta);
    alloc1_kernel<<<NSUMS, 256, 0, stream>>>(meta, bsum);
    alloc2_kernel<<<1, 256, 0, stream>>>(bsum);
    fill_kernel<<<NBLK, 256, 0, stream>>>(feats, staging, bsum, meta,
                                          entries16, entriesF);
    gather_kernel<<<NBLK, 256, 0, stream>>>(entries16, entriesF, meta, bsum,
                                            out);
}

// Round 14
// 179.397 us; speedup vs baseline: 1.0102x; 1.0102x over previous
//
#include <hip/hip_runtime.h>
#include <hip/hip_fp16.h>
#include <math.h>

#define H 256
#define W 256
#define HW (H * W)
#define B 2
#define V 3
#define BV (B * V)
#define C 32
#define RADIUS 1.5f
#define TAU 1.0f
#define EPS 1e-8f

#define NPIX (BV * HW)    // 393216 destination pixels (= source points)
#define NBLK (NPIX / 256) // 1536 (divisible by 8 -> bijective XCD swizzle)

// Cell grid: one bin per ROUNDED projected position, 1-pixel halo.
#define GW 258
#define GH 258
#define NCELL (BV * GH * GW)           // 399384 cells (+1 sentinel)
#define NSUMS ((NCELL + 255) / 256)    // 1561 alloc blocks
#define ECAP 384                       // staged entries per tile halo (mean ~295)

// XCD-aware chunked swizzle (NBLK divisible by 8 -> bijective).
__device__ __forceinline__ int swizzle_block(int bid) {
    return (bid & 7) * (NBLK / 8) + (bid >> 3);
}

// ---------------------------------------------------------------------------
// Fold the projection chain into one matrix (per bv):
//   M = K[b] * dst_RT[b] * src_RTinv[b,v] * inv(K[b])
// Executed by thread 0 of each project block (~400 serial FLOPs, hidden by
// co-resident blocks). NO separate setup dispatch, NO fences.
// ---------------------------------------------------------------------------
__device__ void compute_M(int bv, const float* __restrict__ Kmat,
                          const float* __restrict__ srcRTinv,
                          const float* __restrict__ dstRT,
                          float* __restrict__ Mout) {
    int b = bv / V;
    float a[4][8];
    for (int i = 0; i < 4; i++)
        for (int j = 0; j < 4; j++) {
            a[i][j] = Kmat[b * 16 + i * 4 + j];
            a[i][4 + j] = (i == j) ? 1.0f : 0.0f;
        }
    for (int col = 0; col < 4; col++) {
        int piv = col;
        float best = fabsf(a[col][col]);
        for (int r = col + 1; r < 4; r++) {
            float v = fabsf(a[r][col]);
            if (v > best) { best = v; piv = r; }
        }
        if (piv != col) {
            for (int j = 0; j < 8; j++) {
                float t = a[col][j]; a[col][j] = a[piv][j]; a[piv][j] = t;
            }
        }
        float s = 1.0f / a[col][col];
        for (int j = 0; j < 8; j++) a[col][j] *= s;
        for (int r = 0; r < 4; r++) {
            if (r == col) continue;
            float m = a[r][col];
            for (int j = 0; j < 8; j++) a[r][j] -= m * a[col][j];
        }
    }
    float Kinv[16];
    for (int i = 0; i < 4; i++)
        for (int j = 0; j < 4; j++) Kinv[i * 4 + j] = a[i][4 + j];

    float T1[16];
    const float* S = srcRTinv + bv * 16;
    for (int i = 0; i < 4; i++)
        for (int j = 0; j < 4; j++) {
            float acc = 0.0f;
            for (int k = 0; k < 4; k++) acc += S[i * 4 + k] * Kinv[k * 4 + j];
            T1[i * 4 + j] = acc;
        }
    float T2[16];
    const float* D = dstRT + b * 16;
    for (int i = 0; i < 4; i++)
        for (int j = 0; j < 4; j++) {
            float acc = 0.0f;
            for (int k = 0; k < 4; k++) acc += D[i * 4 + k] * T1[k * 4 + j];
            T2[i * 4 + j] = acc;
        }
    const float* Kb = Kmat + b * 16;
    for (int i = 0; i < 4; i++)
        for (int j = 0; j < 4; j++) {
            float acc = 0.0f;
            for (int k = 0; k < 4; k++) acc += Kb[i * 4 + k] * T2[k * 4 + j];
            Mout[i * 4 + j] = acc;
        }
}

// ---------------------------------------------------------------------------
// Pass 1: setup-M (thread 0 -> LDS) + project + count. Writes ONE coalesced
// 16B staging record per point {px, py, z, cell_as_bits} (cell = -1 if the
// point can't touch any in-image tap) and bumps the cell count. Later passes
// COPY from staging (never reproject) => bit-identical by construction.
// ---------------------------------------------------------------------------
__global__ __launch_bounds__(256) void project_count_kernel(
    const float* __restrict__ depths, const float* __restrict__ Kmat,
    const float* __restrict__ srcRTinv, const float* __restrict__ dstRT,
    float4* __restrict__ staging, int2* __restrict__ meta) {
    __shared__ float Msh[16];
    int gid = swizzle_block(blockIdx.x) * 256 + threadIdx.x;
    int bv = gid >> 16;
    int n = gid & (HW - 1);
    if (threadIdx.x == 0) compute_M(bv, Kmat, srcRTinv, dstRT, Msh);
    __syncthreads();

    float xn = (float)(n & (W - 1)) * (2.0f / (W - 1)) - 1.0f;
    float yn = (float)(n >> 8)      * (2.0f / (H - 1)) - 1.0f;
    float d = depths[gid];
    float X = xn * d, Y = yn * d;
    float p0 = Msh[0] * X + Msh[1] * Y + Msh[2]  * d + Msh[3];
    float p1 = Msh[4] * X + Msh[5] * Y + Msh[6]  * d + Msh[7];
    float z  = Msh[8] * X + Msh[9] * Y + Msh[10] * d + Msh[11];

    int cell = -1;
    float px = 0.0f, py = 0.0f;
    if (z > 0.0f) {  // reference masks z<=0 taps entirely
        float inv = 1.0f / (z + EPS);
        px = (p0 * inv + 1.0f) * 0.5f * (float)(W - 1);
        py = (p1 * inv + 1.0f) * 0.5f * (float)(H - 1);
        float rx = rintf(px), ry = rintf(py);
        // rounding outside the 1-px halo -> no in-image tap with weight > 0
        if (rx >= -1.0f && rx <= (float)W && ry >= -1.0f && ry <= (float)H) {
            cell = bv * (GH * GW) + ((int)ry + 1) * GW + ((int)rx + 1);
            atomicAdd(&meta[cell].y, 1);
        }
    }
    staging[gid] = make_float4(px, py, z, __int_as_float(cell));
}

// ---------------------------------------------------------------------------
// Pass 2a: block-local exclusive scan of counts. meta[i].x = local exclusive
// offset within this 256-cell block; bsum[blk] = block total. DETERMINISTIC
// (no global atomic) so the final CSR is in cell order => start(c+1)==end(c)
// for ALL cells. Covers i == NCELL (sentinel, count 0 from memset).
// SEPARATE dispatch from 2b: r11 measured per-block device fences at 128us;
// a 1-block dispatch is ~2-3us. Do NOT fuse.
// ---------------------------------------------------------------------------
__global__ __launch_bounds__(256) void alloc1_kernel(int2* __restrict__ meta,
                                                     int* __restrict__ bsum) {
    int i = blockIdx.x * 256 + threadIdx.x;
    int c = (i < NCELL) ? meta[i].y : 0;
    int lane = threadIdx.x & 63;
    int wid = threadIdx.x >> 6;
    int x = c;  // inclusive scan within wave
#pragma unroll
    for (int dlt = 1; dlt < 64; dlt <<= 1) {
        int y = __shfl_up(x, dlt);
        if (lane >= dlt) x += y;
    }
    __shared__ int wsum[4];
    __shared__ int wbase[4];
    if (lane == 63) wsum[wid] = x;
    __syncthreads();
    if (threadIdx.x == 0) {
        int s0 = wsum[0], s1 = wsum[1], s2 = wsum[2], s3 = wsum[3];
        wbase[0] = 0; wbase[1] = s0; wbase[2] = s0 + s1; wbase[3] = s0 + s1 + s2;
        bsum[blockIdx.x] = s0 + s1 + s2 + s3;
    }
    __syncthreads();
    if (i <= NCELL) meta[i].x = wbase[wid] + (x - c);
}

// ---------------------------------------------------------------------------
// Pass 2b: exclusive scan of the 1561 block sums, single block, serial
// chunks of 256 with a running carry.
// ---------------------------------------------------------------------------
__global__ __launch_bounds__(256) void alloc2_kernel(int* __restrict__ bsum) {
    __shared__ int wsum[4];
    __shared__ int wbase[4];
    __shared__ int carry_s;
    int tid = threadIdx.x;
    int lane = tid & 63;
    int wid = tid >> 6;
    if (tid == 0) carry_s = 0;
    __syncthreads();
    const int nchunk = (NSUMS + 255) / 256;
    for (int ch = 0; ch < nchunk; ch++) {
        int i = ch * 256 + tid;
        int c = (i < NSUMS) ? bsum[i] : 0;
        int x = c;
#pragma unroll
        for (int dlt = 1; dlt < 64; dlt <<= 1) {
            int y = __shfl_up(x, dlt);
            if (lane >= dlt) x += y;
        }
        if (lane == 63) wsum[wid] = x;
        __syncthreads();
        if (tid == 0) {
            int cr = carry_s;
            int s0 = wsum[0], s1 = wsum[1], s2 = wsum[2], s3 = wsum[3];
            wbase[0] = cr; wbase[1] = cr + s0; wbase[2] = cr + s0 + s1;
            wbase[3] = cr + s0 + s1 + s2;
            carry_s = cr + s0 + s1 + s2 + s3;
        }
        __syncthreads();
        if (i < NSUMS) bsum[i] = wbase[wid] + (x - c);
        __syncthreads();
    }
}

// ---------------------------------------------------------------------------
// Pass 3: fill (absorbs the transpose). Per block: LDS-stage a 256-point
// feats chunk (coalesced), then each thread copies its point's staging
// record to entries16[pos] = {px,py,z, wd=exp(-tau*z)} and writes the 64B
// fp16 feature record at entriesF[pos]. pos = scanned block base + local
// atomic bump => CSR in cell order. The scattered 64B record writes are
// full-sector (64B-aligned) => no write amplification (r9 measured).
// ---------------------------------------------------------------------------
__global__ __launch_bounds__(256) void fill_kernel(
    const float* __restrict__ feats, const float4* __restrict__ staging,
    const int* __restrict__ bsum, int2* __restrict__ meta,
    float4* __restrict__ entries16, uint4* __restrict__ entriesF) {
    __shared__ float sm[C][257];
    int blk = blockIdx.x;
    int bv = blk >> 8;
    int n0 = (blk & 255) << 8;
    int tid = threadIdx.x;
    const float* src = feats + (size_t)bv * C * HW + n0;
#pragma unroll
    for (int c = 0; c < C; c++) sm[c][tid] = src[(size_t)c * HW + tid];
    __syncthreads();

    int gid = (bv << 16) | (n0 + tid);
    float4 s = staging[gid];
    int cell = __float_as_int(s.w);
    if (cell < 0) return;
    int pos = bsum[cell >> 8] + atomicAdd(&meta[cell].x, 1);

    float wd = expf(-TAU * s.z);  // once per point (not per tap)
    entries16[pos] = make_float4(s.x, s.y, s.z, wd);

    uint4* dst = entriesF + (size_t)pos * 4;
#pragma unroll
    for (int g = 0; g < 4; g++) {
        __half2 h0 = __floats2half2_rn(sm[g * 8 + 0][tid], sm[g * 8 + 1][tid]);
        __half2 h1 = __floats2half2_rn(sm[g * 8 + 2][tid], sm[g * 8 + 3][tid]);
        __half2 h2 = __floats2half2_rn(sm[g * 8 + 4][tid], sm[g * 8 + 5][tid]);
        __half2 h3 = __floats2half2_rn(sm[g * 8 + 6][tid], sm[g * 8 + 7][tid]);
        uint4 pk;
        pk.x = *(unsigned int*)&h0;
        pk.y = *(unsigned int*)&h1;
        pk.z = *(unsigned int*)&h2;
        pk.w = *(unsigned int*)&h3;
        dst[g] = pk;  // 64B record, 64B-aligned
    }
}

// ---------------------------------------------------------------------------
// Pass 4: TILED gather (r12 structure = best measured). Block = 16x16 pixel
// tile; 18 contiguous CSR row-ranges staged to LDS (test + fp16 features,
// coalesced). Phase A2 is a wave-parallel scan. Per-entry body is
// branch-free: w == 0 exactly on rejects, so loads+FMA run unconditionally
// (exact result). x2 unrolled for batched LDS waits.
// ---------------------------------------------------------------------------
__global__ __launch_bounds__(256) void gather_kernel(
    const float4* __restrict__ entries16, const uint4* __restrict__ entriesF,
    const int2* __restrict__ meta, const int* __restrict__ bsum,
    float* __restrict__ out) {
    __shared__ int cs_s[18][19];
    __shared__ int row_rs[18];   // global CSR start of row
    __shared__ int row_off[18];  // compact LDS offset of row
    __shared__ int row_sl[18];   // staged length of row
    __shared__ float4 lds_e[ECAP];
    __shared__ uint4 lds_f[ECAP * 5];  // [idx*5 + g], g in 0..3 (pad slot 4)

    int sblk = swizzle_block(blockIdx.x);
    int bv = sblk >> 8;
    int t = sblk & 255;
    int ty0 = (t >> 4) << 4;   // tile origin in dest coords
    int tx0 = (t & 15) << 4;
    int tid = threadIdx.x;
    int cellbase = bv * (GH * GW);

    // Phase A: global CSR start offset for each of the 18x19 halo cells.
    // Column 18 = start of the next linear cell == end of column 17
    // (contiguity); the +1 sentinel cell (== total) covers the last span.
    for (int i = tid; i < 18 * 19; i += 256) {
        int hr = i / 19, lc = i - hr * 19;
        int cg = cellbase + (ty0 + hr) * GW + (tx0 + lc);
        int2 m = meta[cg];
        cs_s[hr][lc] = bsum[cg >> 8] + m.x - m.y;  // after fill: x=end(local)
    }
    __syncthreads();
    // Phase A2: wave-parallel packing-offset scan over the 18 rows.
    if (tid < 32) {
        int l = tid;
        int start = 0, len = 0;
        if (l < 18) { start = cs_s[l][0]; len = cs_s[l][18] - start; }
        int x = len;
#pragma unroll
        for (int dlt = 1; dlt < 32; dlt <<= 1) {
            int y = __shfl_up(x, dlt);
            if (l >= dlt) x += y;
        }
        if (l < 18) {
            int off = x - len;
            row_rs[l] = start;
            row_off[l] = off;
            int sl = ECAP - off;
            sl = min(sl, len);
            if (sl < 0) sl = 0;
            row_sl[l] = sl;
        }
    }
    __syncthreads();
    // Phase B: stage test + feature records; wave w handles rows w, w+4, ...
    {
        int wid = tid >> 6, lane = tid & 63;
        for (int hr = wid; hr < 18; hr += 4) {
            int rs = row_rs[hr], off = row_off[hr], sl = row_sl[hr];
            for (int j = lane; j < sl; j += 64)
                lds_e[off + j] = entries16[rs + j];
            int j0 = lane >> 2, g = lane & 3;
            for (int j = j0; j < sl; j += 16)  // 64 lanes = 1KB contiguous
                lds_f[(off + j) * 5 + g] = entriesF[(size_t)(rs + j) * 4 + g];
        }
    }
    __syncthreads();

    int lx = tid & 15, ly = tid >> 4;
    float qx = (float)(tx0 + lx);
    float qy = (float)(ty0 + ly);

    float wsum = 0.0f, zwsum = 0.0f;
    float facc[C];
#pragma unroll
    for (int c = 0; c < C; c++) facc[c] = 0.0f;

    // Branch-free LDS body: w == 0 exactly for rejected entries.
    auto body = [&](int li) {
        float4 v = lds_e[li];
        uint4 fv0 = lds_f[li * 5 + 0];
        uint4 fv1 = lds_f[li * 5 + 1];
        uint4 fv2 = lds_f[li * 5 + 2];
        uint4 fv3 = lds_f[li * 5 + 3];
        float ddx = qx - v.x, ddy = qy - v.y;
        float dist = sqrtf(ddx * ddx + ddy * ddy + EPS);
        float wr = fmaxf(0.0f, 1.0f - dist * (1.0f / RADIUS));
        float w = wr * v.w;  // v.w = exp(-tau*z); w = 0 on reject
        wsum += w;
        zwsum += v.z * w;
        const uint4* fvs[4] = {&fv0, &fv1, &fv2, &fv3};
#pragma unroll
        for (int g = 0; g < 4; g++) {
            const __half2* h2 = (const __half2*)fvs[g];
#pragma unroll
            for (int k = 0; k < 4; k++) {
                float2 f2 = __half22float2(h2[k]);
                facc[g * 8 + 2 * k]     = fmaf(w, f2.x, facc[g * 8 + 2 * k]);
                facc[g * 8 + 2 * k + 1] = fmaf(w, f2.y, facc[g * 8 + 2 * k + 1]);
            }
        }
    };
    auto accum_glb = [&](int pos) {  // exact overflow fallback (rare)
        float4 v = entries16[pos];
        float ddx = qx - v.x, ddy = qy - v.y;
        float d2 = ddx * ddx + ddy * ddy + EPS;
        if (d2 < RADIUS * RADIUS) {
            float dist = sqrtf(d2);
            float wr = 1.0f - dist * (1.0f / RADIUS);
            float w = wr * v.w;
            wsum += w;
            zwsum += v.z * w;
            const uint4* fp = entriesF + (size_t)pos * 4;
#pragma unroll
            for (int g = 0; g < 4; g++) {
                uint4 fv = fp[g];
                const __half2* h2 = (const __half2*)&fv;
#pragma unroll
                for (int k = 0; k < 4; k++) {
                    float2 f2 = __half22float2(h2[k]);
                    facc[g * 8 + 2 * k]     = fmaf(w, f2.x, facc[g * 8 + 2 * k]);
                    facc[g * 8 + 2 * k + 1] = fmaf(w, f2.y, facc[g * 8 + 2 * k + 1]);
                }
            }
        }
    };

#pragma unroll
    for (int dy = 0; dy < 3; dy++) {
        int hr = ly + dy;
        int s = cs_s[hr][lx];
        int e = cs_s[hr][lx + 3];
        int rs = row_rs[hr];
        int off = row_off[hr];
        int sEnd = rs + row_sl[hr];
        int e1 = min(e, sEnd);
        int li0 = off + (s - rs);
        int cnt = e1 - s;
        int j = 0;
        for (; j + 2 <= cnt; j += 2) {  // x2 unrolled, independent bodies
            body(li0 + j);
            body(li0 + j + 1);
        }
        if (j < cnt) body(li0 + j);
        for (int pos = max(s, sEnd); pos < e; ++pos) accum_glb(pos);
    }

    int q = ((ty0 + ly) << 8) | (tx0 + lx);
    int gid = (bv << 16) | q;
    float invw = 1.0f / (wsum + EPS);
    float* ob = out + (size_t)bv * C * HW + q;
#pragma unroll
    for (int c = 0; c < C; c++) ob[(size_t)c * HW] = facc[c] * invw;
    out[(size_t)BV * C * HW + gid] = zwsum * invw;
}

extern "C" void kernel_launch(void* const* d_in, const int* in_sizes, int n_in,
                              void* d_out, int out_size, void* d_ws, size_t ws_size,
                              hipStream_t stream) {
    const float* depths   = (const float*)d_in[0];  // (B,V,1,H,W)
    const float* feats    = (const float*)d_in[1];  // (B,V,C,H,W)
    const float* Kmat     = (const float*)d_in[2];  // (B,4,4)
    const float* srcRTinv = (const float*)d_in[4];  // (B,V,4,4)
    const float* dstRT    = (const float*)d_in[5];  // (B,1,4,4)
    float* out = (float*)d_out;

    // ws layout:
    //   entriesF  : NPIX * 64B fp16 records (CSR pos-indexed)  25.17 MB
    //   entries16 : NPIX * float4 {px,py,z,wd}                  6.29 MB
    //   staging   : NPIX * float4 {px,py,z,cell}                6.29 MB
    //   meta      : (NCELL+1) int2 {ofs,cnt}                    3.20 MB
    //   bsum      : NSUMS int                                   6.2 KB
    // total ~41 MB (<= 63 MB proven available)
    char* ws = (char*)d_ws;
    size_t off_entriesF = 0;
    size_t off_entries16 = off_entriesF + (size_t)NPIX * 64;
    size_t off_staging = off_entries16 + (size_t)NPIX * 16;
    size_t off_meta = off_staging + (size_t)NPIX * 16;
    size_t off_bsum = off_meta + (size_t)(NCELL + 1) * 8;
    size_t needed = off_bsum + (size_t)NSUMS * 4 + 16;

    if (ws_size < needed) {
        hipMemsetAsync(d_out, 0, (size_t)out_size * 4, stream);
        return;
    }

    uint4* entriesF   = (uint4*)(ws + off_entriesF);
    float4* entries16 = (float4*)(ws + off_entries16);
    float4* staging   = (float4*)(ws + off_staging);
    int2* meta        = (int2*)(ws + off_meta);
    int* bsum         = (int*)(ws + off_bsum);

    // zero meta {ofs,cnt} incl. sentinel (bsum fully written by alloc1)
    hipMemsetAsync(meta, 0, (size_t)(NCELL + 1) * 8, stream);
    project_count_kernel<<<NBLK, 256, 0, stream>>>(depths, Kmat, srcRTinv,
                                                   dstRT, staging, meta);
    alloc1_kernel<<<NSUMS, 256, 0, stream>>>(meta, bsum);
    alloc2_kernel<<<1, 256, 0, stream>>>(bsum);
    fill_kernel<<<NBLK, 256, 0, stream>>>(feats, staging, bsum, meta,
                                          entries16, entriesF);
    gather_kernel<<<NBLK, 256, 0, stream>>>(entries16, entriesF, meta, bsum,
                                            out);
}